// Round 5
// baseline (361.407 us; speedup 1.0000x reference)
//
#include <hip/hip_runtime.h>
#include <math.h>

#define TPB 512
#define LDM 72   // bf16 row stride: 144 B -> 16B-aligned b128, 2-way-free banks

// ---------------------------------------------------------------------------
// N=129, B=128, D=64, NOUT=65, NIN=64, NMID=63
// x: (129,128,2) fp32 | mps_input: (64,64,64,2) | mps_output: (65,64,64,2,2)
// out: 129 fp32 = out[0..127] per-batch, out[128] = lnrm
//
// Congruence S <- sum_g G^T S G (S symmetric) via bf16 MFMA 16x16x32.
// Phase-latency law (R2/R4 fit): dur = chain-phases x per-phase latency.
// This round: every phase uses all 8 waves; cross-gen sums in-register
// (no partial reduction); builds run from prefetched VGPRs in store phases.
// Storage: Sb[r][c] (sym), G/U col-major (storage row = matrix col).
// ---------------------------------------------------------------------------

typedef __attribute__((ext_vector_type(8))) short bf16x8;
typedef __attribute__((ext_vector_type(4))) float f32x4;
typedef unsigned short US;

__device__ __forceinline__ US f2b(float f) {
    union { float f; unsigned u; } v; v.f = f;
    return (US)((v.u + 0x7FFFu + ((v.u >> 16) & 1u)) >> 16);
}
__device__ __forceinline__ float bf2f(US h) {
    union { unsigned u; float f; } v; v.u = ((unsigned)h) << 16; return v.f;
}

// stage1: U[:, n0..n0+15] = S(rows M0..M0+16*NMT-1) x G[:, n0..]; write U col-major
template<int NMT>
__device__ __forceinline__ void s1_strip(const US* S, const US* G, US* U,
                                         int M0, int n0, int lane) {
    const int ml = lane & 15;
    const int q8 = (lane >> 4) << 3;
    const int q4 = (lane >> 4) << 2;
    const US* gb = G + (n0 + ml) * LDM + q8;
    bf16x8 b0 = *(const bf16x8*)(gb);
    bf16x8 b1 = *(const bf16x8*)(gb + 32);
#pragma unroll
    for (int mt = 0; mt < NMT; ++mt) {
        const US* ab = S + (M0 + mt * 16 + ml) * LDM + q8;
        bf16x8 a0 = *(const bf16x8*)(ab);
        bf16x8 a1 = *(const bf16x8*)(ab + 32);
        f32x4 d = {0.f, 0.f, 0.f, 0.f};
        d = __builtin_amdgcn_mfma_f32_16x16x32_bf16(a0, b0, d, 0, 0, 0);
        d = __builtin_amdgcn_mfma_f32_16x16x32_bf16(a1, b1, d, 0, 0, 0);
        ushort4 wv;
        wv.x = f2b(d.x); wv.y = f2b(d.y); wv.z = f2b(d.z); wv.w = f2b(d.w);
        *(ushort4*)(U + (n0 + ml) * LDM + M0 + mt * 16 + q4) = wv;
    }
}

// stage2 half-unit: acc[2] += (G^T U)[R0..R0+31][C0..C0+15]; G,U col-major
__device__ __forceinline__ void s2_half(const US* G, const US* U, f32x4 acc[2],
                                        int R0, int C0, int lane) {
    const int ml = lane & 15;
    const int q8 = (lane >> 4) << 3;
    const US* ub = U + (C0 + ml) * LDM + q8;
    bf16x8 b0 = *(const bf16x8*)(ub);
    bf16x8 b1 = *(const bf16x8*)(ub + 32);
#pragma unroll
    for (int rt = 0; rt < 2; ++rt) {
        const US* ab = G + (R0 + 16 * rt + ml) * LDM + q8;
        bf16x8 a0 = *(const bf16x8*)(ab);
        bf16x8 a1 = *(const bf16x8*)(ab + 32);
        acc[rt] = __builtin_amdgcn_mfma_f32_16x16x32_bf16(a0, b0, acc[rt], 0, 0, 0);
        acc[rt] = __builtin_amdgcn_mfma_f32_16x16x32_bf16(a1, b1, acc[rt], 0, 0, 0);
    }
}

__device__ __forceinline__ void storeHalf(US* Sb, const f32x4 acc[2], float s,
                                          int R0, int C0, int lane) {
    const int ml = lane & 15;
    const int q4 = (lane >> 4) << 2;
#pragma unroll
    for (int rt = 0; rt < 2; ++rt) {
        ushort4 wv;
        wv.x = f2b(acc[rt].x * s); wv.y = f2b(acc[rt].y * s);
        wv.z = f2b(acc[rt].z * s); wv.w = f2b(acc[rt].w * s);
        *(ushort4*)(Sb + (C0 + ml) * LDM + R0 + 16 * rt + q4) = wv;
    }
}

__device__ __forceinline__ float wavemax8(const f32x4 a[2]) {
    float m = 0.f;
#pragma unroll
    for (int rt = 0; rt < 2; ++rt)
        m = fmaxf(m, fmaxf(fmaxf(fabsf(a[rt].x), fabsf(a[rt].y)),
                           fmaxf(fabsf(a[rt].z), fabsf(a[rt].w))));
#pragma unroll
    for (int off = 32; off; off >>= 1) m = fmaxf(m, __shfl_down(m, off, 64));
    return m;
}

__global__ __launch_bounds__(TPB)
void mps_proj_kernel(const float* __restrict__ x,
                     const float* __restrict__ mi,
                     const float* __restrict__ mo,
                     float* __restrict__ out) {
    __shared__ __align__(16) US smem[9 * 64 * LDM];   // S | U0..U3 | G0..G3
    US* const Sb = smem;
#define UsP(g) (smem + (1 + (g)) * 64 * LDM)
#define GsP(g) (smem + (5 + (g)) * 64 * LDM)
    __shared__ float fsA[256];
    __shared__ float fsr[8];
    __shared__ float fsv[128];

    const int tid  = threadIdx.x;
    const int lane = tid & 63;
    const int w    = tid >> 6;              // wave id 0..7
    const int rr   = tid & 63;              // builder storage row
    const int R0h  = (w & 1) * 32;          // stage2 half-unit coords (all waves)
    const int C0h  = (w >> 1) * 16;

    const float2* mi2 = (const float2*)mi;
    const float4* mo4 = (const float4*)mo;

    if (blockIdx.x < 128) {
        // =================== per-batch MPS scan, b = blockIdx.x ==================
        const int b = blockIdx.x;
        const float xa = x[b * 2 + 0], xb = x[b * 2 + 1];
        if (tid < 64) {
            float4 v = mo4[tid];
            fsA[tid * 2 + 0] = xa * v.x + xb * v.z;
            fsA[tid * 2 + 1] = xa * v.y + xb * v.w;
        }
        __syncthreads();
        float vals[8]; float mloc = 0.f;
#pragma unroll
        for (int j = 0; j < 8; ++j) {
            int pos = tid + j * TPB; int u = pos >> 6, d = pos & 63;
            float s = fsA[u * 2] * fsA[d * 2] + fsA[u * 2 + 1] * fsA[d * 2 + 1];
            vals[j] = s; mloc = fmaxf(mloc, fabsf(s));
        }
#pragma unroll
        for (int off = 32; off; off >>= 1) mloc = fmaxf(mloc, __shfl_down(mloc, off, 64));
        if (lane == 0) fsr[w] = mloc;
        __syncthreads();
        float amax = fsr[0];
#pragma unroll
        for (int i = 1; i < 8; ++i) amax = fmaxf(amax, fsr[i]);
        float logsum = logf(amax);
        float inv = 1.f / amax;
#pragma unroll
        for (int j = 0; j < 8; ++j) {
            int pos = tid + j * TPB;
            Sb[(pos >> 6) * LDM + (pos & 63)] = f2b(vals[j] * inv);
        }
        // build G(k=0) direct: G0=Ain(0), G1=X0(1), G2=X1(1)
        {
            const float x1a = x[1 * 256 + b * 2 + 0], x1b = x[1 * 256 + b * 2 + 1];
            const float x0a = x[2 * 256 + b * 2 + 0], x0b = x[2 * 256 + b * 2 + 1];
            const float2* si = mi2;
            const float4* so = mo4 + 4096;
#pragma unroll
            for (int p = 0; p < 2; ++p) {
                const int d0 = (w << 2) + (p << 5);
                ushort4 w0, w1, w2;
#pragma unroll
                for (int i = 0; i < 4; ++i) {
                    float2 mv = si[(d0 + i) * 64 + rr];
                    ((US*)&w0)[i] = f2b(x1a * mv.x + x1b * mv.y);
                    float4 ov = so[(d0 + i) * 64 + rr];
                    ((US*)&w1)[i] = f2b(x0a * ov.x + x0b * ov.z);
                    ((US*)&w2)[i] = f2b(x0a * ov.y + x0b * ov.w);
                }
                *(ushort4*)(GsP(0) + rr * LDM + d0) = w0;
                *(ushort4*)(GsP(1) + rr * LDM + d0) = w1;
                *(ushort4*)(GsP(2) + rr * LDM + d0) = w2;
            }
        }
        __syncthreads();

        float2 pfi[2][4]; float4 pfo[2][4];
        for (int k = 0; k < 63; ++k) {
            // prefetch site k+1's tensors (consumed in P5 build)
            if (k < 62) {
                const float2* si = mi2 + (k + 1) * 4096;
                const float4* so = mo4 + (k + 2) * 4096;
#pragma unroll
                for (int p = 0; p < 2; ++p) {
                    const int d0 = (w << 2) + (p << 5);
#pragma unroll
                    for (int i = 0; i < 4; ++i) {
                        pfi[p][i] = si[(d0 + i) * 64 + rr];
                        pfo[p][i] = so[(d0 + i) * 64 + rr];
                    }
                }
            }
            // P1: U0 = S * Ain   (8 waves: 32-row x 16-col blocks)
            { const int mh = w & 1, nt = w >> 1;
              s1_strip<2>(Sb, GsP(0), UsP(0), mh * 32, nt * 16, lane); }
            __syncthreads();
            // P2: S' = Ain^T U0 (unscaled), 8 half-units
            {
                f32x4 sacc[2];
                sacc[0] = sacc[1] = (f32x4){0.f, 0.f, 0.f, 0.f};
                s2_half(GsP(0), UsP(0), sacc, R0h, C0h, lane);
                storeHalf(Sb, sacc, 1.f, R0h, C0h, lane);
            }
            __syncthreads();
            // P3: U_t = S' * X_t  (2 gens x 4 col-strips)
            { const int g = w >> 2, nt = w & 3;
              s1_strip<4>(Sb, GsP(1 + g), UsP(g), 0, nt * 16, lane); }
            __syncthreads();
            // P4: acc = sum_t X_t^T U_t per half-unit (in-reg gen sum); local max
            f32x4 acc[2];
            acc[0] = acc[1] = (f32x4){0.f, 0.f, 0.f, 0.f};
            s2_half(GsP(1), UsP(0), acc, R0h, C0h, lane);
            s2_half(GsP(2), UsP(1), acc, R0h, C0h, lane);
            { float m = wavemax8(acc); if (lane == 0) fsr[w] = m; }
            __syncthreads();
            // P5: amax; scaled store; build G(k+1) from prefetched regs
            amax = fsr[0];
#pragma unroll
            for (int i = 1; i < 8; ++i) amax = fmaxf(amax, fsr[i]);
            logsum += logf(amax);
            storeHalf(Sb, acc, 1.f / amax, R0h, C0h, lane);
            if (k < 62) {
                const float x1a = x[(2 * k + 3) * 256 + b * 2 + 0];
                const float x1b = x[(2 * k + 3) * 256 + b * 2 + 1];
                const float x0a = x[(2 * k + 4) * 256 + b * 2 + 0];
                const float x0b = x[(2 * k + 4) * 256 + b * 2 + 1];
#pragma unroll
                for (int p = 0; p < 2; ++p) {
                    const int d0 = (w << 2) + (p << 5);
                    ushort4 w0, w1, w2;
#pragma unroll
                    for (int i = 0; i < 4; ++i) {
                        float2 mv = pfi[p][i];
                        ((US*)&w0)[i] = f2b(x1a * mv.x + x1b * mv.y);
                        float4 ov = pfo[p][i];
                        ((US*)&w1)[i] = f2b(x0a * ov.x + x0b * ov.z);
                        ((US*)&w2)[i] = f2b(x0a * ov.y + x0b * ov.w);
                    }
                    *(ushort4*)(GsP(0) + rr * LDM + d0) = w0;
                    *(ushort4*)(GsP(1) + rr * LDM + d0) = w1;
                    *(ushort4*)(GsP(2) + rr * LDM + d0) = w2;
                }
            }
            __syncthreads();
        }

        // ---- last site: out[b] = logsum + log(sum_i v_i^T S v_i) ----
        {
            const float x1a = x[127 * 256 + b * 2 + 0];
            const float x1b = x[127 * 256 + b * 2 + 1];
            const float x0a = x[128 * 256 + b * 2 + 0];
            const float x0b = x[128 * 256 + b * 2 + 1];
            if (tid < 64) {                       // w[r][i]
                float4 v = mo4[64 * 4096 + tid * 64];
                fsA[tid * 2 + 0] = x0a * v.x + x0b * v.z;
                fsA[tid * 2 + 1] = x0a * v.y + x0b * v.w;
            }
            {                                     // Ain63 -> G0 (col-major bf16)
                const float2* si = mi2 + 63 * 4096;
#pragma unroll
                for (int p = 0; p < 2; ++p) {
                    const int d0 = (w << 2) + (p << 5);
                    ushort4 w0;
#pragma unroll
                    for (int i = 0; i < 4; ++i) {
                        float2 mv = si[(d0 + i) * 64 + rr];
                        ((US*)&w0)[i] = f2b(x1a * mv.x + x1b * mv.y);
                    }
                    *(ushort4*)(GsP(0) + rr * LDM + d0) = w0;
                }
            }
            __syncthreads();
            if (tid < 128) {                      // v[d][i] = sum_r Ain[d][r] w[r][i]
                int dd = tid >> 1, ii = tid & 1;
                float s = 0.f;
                for (int r = 0; r < 64; ++r) s += bf2f(GsP(0)[r * LDM + dd]) * fsA[r * 2 + ii];
                fsv[tid] = s;
            }
            __syncthreads();
            float part = 0.f;
#pragma unroll
            for (int j = 0; j < 8; ++j) {
                int pos = tid + j * TPB; int dd = pos >> 6, uu = pos & 63;
                part += bf2f(Sb[dd * LDM + uu]) *
                        (fsv[dd * 2] * fsv[uu * 2] + fsv[dd * 2 + 1] * fsv[uu * 2 + 1]);
            }
#pragma unroll
            for (int off = 32; off; off >>= 1) part += __shfl_down(part, off, 64);
            if (lane == 0) fsr[w] = part;
            __syncthreads();
            if (tid == 0) {
                float t = 0.f;
#pragma unroll
                for (int i = 0; i < 8; ++i) t += fsr[i];
                out[b] = logsum + logf(t);
            }
        }
    } else {
        // ============================ lnrm scalar chain ==========================
        if (tid < 64) {
            float4 v = mo4[tid];
            fsA[tid * 4 + 0] = v.x; fsA[tid * 4 + 1] = v.y;
            fsA[tid * 4 + 2] = v.z; fsA[tid * 4 + 3] = v.w;
        }
        __syncthreads();
        float vals[8]; float mloc = 0.f;
#pragma unroll
        for (int j = 0; j < 8; ++j) {
            int pos = tid + j * TPB; int kk = pos >> 6, ll = pos & 63;
            float s = fsA[kk * 4 + 0] * fsA[ll * 4 + 0] + fsA[kk * 4 + 1] * fsA[ll * 4 + 1] +
                      fsA[kk * 4 + 2] * fsA[ll * 4 + 2] + fsA[kk * 4 + 3] * fsA[ll * 4 + 3];
            vals[j] = s; mloc = fmaxf(mloc, fabsf(s));
        }
#pragma unroll
        for (int off = 32; off; off >>= 1) mloc = fmaxf(mloc, __shfl_down(mloc, off, 64));
        if (lane == 0) fsr[w] = mloc;
        __syncthreads();
        float amax = fsr[0];
#pragma unroll
        for (int i = 1; i < 8; ++i) amax = fmaxf(amax, fsr[i]);
        float logsum = logf(amax);
        float inv = 1.f / amax;
#pragma unroll
        for (int j = 0; j < 8; ++j) {
            int pos = tid + j * TPB;
            Sb[(pos >> 6) * LDM + (pos & 63)] = f2b(vals[j] * inv);
        }
        // build in-G(0) direct
        {
            const float2* si = mi2;
#pragma unroll
            for (int p = 0; p < 2; ++p) {
                const int d0 = (w << 2) + (p << 5);
                ushort4 w0, w1;
#pragma unroll
                for (int i = 0; i < 4; ++i) {
                    float2 mv = si[(d0 + i) * 64 + rr];
                    ((US*)&w0)[i] = f2b(mv.x);
                    ((US*)&w1)[i] = f2b(mv.y);
                }
                *(ushort4*)(GsP(0) + rr * LDM + d0) = w0;
                *(ushort4*)(GsP(1) + rr * LDM + d0) = w1;
            }
        }
        __syncthreads();

        float2 pfi[2][4]; float4 pfo[2][4];
        for (int n = 0; n < 64; ++n) {
            // prefetch: mo[n+1] (used P3), mi[n+1] (used P6)
            {
                const float4* so = mo4 + (n + 1) * 4096;
#pragma unroll
                for (int p = 0; p < 2; ++p) {
                    const int d0 = (w << 2) + (p << 5);
#pragma unroll
                    for (int i = 0; i < 4; ++i) pfo[p][i] = so[(d0 + i) * 64 + rr];
                }
                if (n < 63) {
                    const float2* si = mi2 + (n + 1) * 4096;
#pragma unroll
                    for (int p = 0; p < 2; ++p) {
                        const int d0 = (w << 2) + (p << 5);
#pragma unroll
                        for (int i = 0; i < 4; ++i) pfi[p][i] = si[(d0 + i) * 64 + rr];
                    }
                }
            }
            // P1: in-stage1 — U_g = S*G_g (2 gens x 4 col-strips)
            { const int g = w >> 2, nt = w & 3;
              s1_strip<4>(Sb, GsP(g), UsP(g), 0, nt * 16, lane); }
            __syncthreads();
            // P2: in-stage2 — half-units, in-reg gen sum; local max
            f32x4 acc[2];
            acc[0] = acc[1] = (f32x4){0.f, 0.f, 0.f, 0.f};
            s2_half(GsP(0), UsP(0), acc, R0h, C0h, lane);
            s2_half(GsP(1), UsP(1), acc, R0h, C0h, lane);
            { float m = wavemax8(acc); if (lane == 0) fsr[w] = m; }
            __syncthreads();
            // P3: a1; scaled store; build out-G0..3 from pfo
            {
                float a1 = fsr[0];
#pragma unroll
                for (int i = 1; i < 8; ++i) a1 = fmaxf(a1, fsr[i]);
                logsum += logf(a1);
                storeHalf(Sb, acc, 1.f / a1, R0h, C0h, lane);
#pragma unroll
                for (int p = 0; p < 2; ++p) {
                    const int d0 = (w << 2) + (p << 5);
                    ushort4 w0, w1, w2, w3;
#pragma unroll
                    for (int i = 0; i < 4; ++i) {
                        float4 ov = pfo[p][i];
                        ((US*)&w0)[i] = f2b(ov.x); ((US*)&w1)[i] = f2b(ov.y);
                        ((US*)&w2)[i] = f2b(ov.z); ((US*)&w3)[i] = f2b(ov.w);
                    }
                    *(ushort4*)(GsP(0) + rr * LDM + d0) = w0;
                    *(ushort4*)(GsP(1) + rr * LDM + d0) = w1;
                    *(ushort4*)(GsP(2) + rr * LDM + d0) = w2;
                    *(ushort4*)(GsP(3) + rr * LDM + d0) = w3;
                }
            }
            __syncthreads();
            // P4: out-stage1 — U_g = S*G_g (4 gens x 2 col-halves, 2 strips each)
            { const int g = w >> 1, nh = w & 1;
              s1_strip<4>(Sb, GsP(g), UsP(g), 0, nh * 32, lane);
              s1_strip<4>(Sb, GsP(g), UsP(g), 0, nh * 32 + 16, lane); }
            __syncthreads();
            // P5: out-stage2 — half-units, 4-gen in-reg sum; local max
            f32x4 acc2[2];
            acc2[0] = acc2[1] = (f32x4){0.f, 0.f, 0.f, 0.f};
#pragma unroll
            for (int g = 0; g < 4; ++g) s2_half(GsP(g), UsP(g), acc2, R0h, C0h, lane);
            { float m = wavemax8(acc2); if (lane == 0) fsr[w] = m; }
            __syncthreads();
            // P6: a2; scaled store + build in-G(n+1), or final output
            {
                float a2 = fsr[0];
#pragma unroll
                for (int i = 1; i < 8; ++i) a2 = fmaxf(a2, fsr[i]);
                logsum += logf(a2);
                if (n < 63) {
                    storeHalf(Sb, acc2, 1.f / a2, R0h, C0h, lane);
#pragma unroll
                    for (int p = 0; p < 2; ++p) {
                        const int d0 = (w << 2) + (p << 5);
                        ushort4 w0, w1;
#pragma unroll
                        for (int i = 0; i < 4; ++i) {
                            float2 mv = pfi[p][i];
                            ((US*)&w0)[i] = f2b(mv.x);
                            ((US*)&w1)[i] = f2b(mv.y);
                        }
                        *(ushort4*)(GsP(0) + rr * LDM + d0) = w0;
                        *(ushort4*)(GsP(1) + rr * LDM + d0) = w1;
                    }
                } else {
                    // S[0][0]: wave 0 half-unit (R0h=0,C0h=0), lane 0, acc2[0].x
                    if (tid == 0) out[128] = logsum + logf(acc2[0].x / a2);
                }
            }
            __syncthreads();
        }
    }
#undef UsP
#undef GsP
}

extern "C" void kernel_launch(void* const* d_in, const int* in_sizes, int n_in,
                              void* d_out, int out_size, void* d_ws, size_t ws_size,
                              hipStream_t stream) {
    (void)in_sizes; (void)n_in; (void)d_ws; (void)ws_size; (void)out_size;
    const float* x  = (const float*)d_in[0];
    const float* mi = (const float*)d_in[1];
    const float* mo = (const float*)d_in[2];
    float* out = (float*)d_out;
    hipLaunchKernelGGL(mps_proj_kernel, dim3(129), dim3(TPB), 0, stream,
                       x, mi, mo, out);
}